// Round 1
// baseline (524.381 us; speedup 1.0000x reference)
//
#include <hip/hip_runtime.h>

#define C 128
#define HID 256
#define NPB 16   // nodes per block in node_mlp

__global__ __launch_bounds__(256) void edge_scatter(
    const float* __restrict__ x, const int* __restrict__ ei,
    const float* __restrict__ ea, float* __restrict__ agg,
    float* __restrict__ deg, int E)
{
    int e = blockIdx.x * 2 + (threadIdx.x >> 7);
    if (e >= E) return;
    int c = threadIdx.x & 127;
    int src = ei[e];
    int dst = ei[E + e];
    float w = ea[e];
    float v = x[(long)src * C + c] * w;
    atomicAdd(&agg[(long)dst * C + c], v);
    if (c == 0) atomicAdd(&deg[dst], 1.0f);
}

__global__ __launch_bounds__(256) void node_mlp(
    const float* __restrict__ x, const float* __restrict__ deg,
    const float* __restrict__ W1, const float* __restrict__ b1,
    const float* __restrict__ W2, const float* __restrict__ b2,
    float* __restrict__ io, int N)
{
    __shared__ float outS[NPB][C];    // 8 KB
    __shared__ float hS[NPB][HID];    // 16 KB
    const int t = threadIdx.x;
    const long base = (long)blockIdx.x * NPB;

    // ---- Phase A: out = 0.5*(x + agg/max(deg,1)) into LDS ----
    for (int i = t; i < NPB * C; i += 256) {
        int n = i >> 7, c = i & 127;
        long node = base + n;
        float v = 0.0f;
        if (node < N) {
            float d = fmaxf(deg[node], 1.0f);
            float a = io[node * C + c] / d;
            v = 0.5f * (x[node * C + c] + a);
        }
        outS[n][c] = v;
    }
    __syncthreads();

    // ---- Phase B: h = relu(out @ W1 + b1), thread = (col c0, c0+128) x 8 nodes ----
    {
        const int c0 = t & 127;
        const int g  = t >> 7;          // 2 groups of 8 nodes
        float acc[8][2];
        #pragma unroll
        for (int n = 0; n < 8; ++n) { acc[n][0] = 0.f; acc[n][1] = 0.f; }
        for (int k = 0; k < C; k += 4) {
            float w1a[4], w1b[4];
            #pragma unroll
            for (int j = 0; j < 4; ++j) {
                w1a[j] = W1[(k + j) * HID + c0];
                w1b[j] = W1[(k + j) * HID + c0 + 128];
            }
            #pragma unroll
            for (int n = 0; n < 8; ++n) {
                const float4 o4 = *reinterpret_cast<const float4*>(&outS[g * 8 + n][k]);
                acc[n][0] += o4.x * w1a[0] + o4.y * w1a[1] + o4.z * w1a[2] + o4.w * w1a[3];
                acc[n][1] += o4.x * w1b[0] + o4.y * w1b[1] + o4.z * w1b[2] + o4.w * w1b[3];
            }
        }
        const float bb0 = b1[c0];
        const float bb1 = b1[c0 + 128];
        #pragma unroll
        for (int n = 0; n < 8; ++n) {
            hS[g * 8 + n][c0]       = fmaxf(acc[n][0] + bb0, 0.f);
            hS[g * 8 + n][c0 + 128] = fmaxf(acc[n][1] + bb1, 0.f);
        }
    }
    __syncthreads();

    // ---- Phase C: y = h @ W2 + b2, thread = (col c0, c0+64) x 4 nodes ----
    {
        const int c0 = t & 63;
        const int g  = t >> 6;          // 4 groups of 4 nodes
        float acc[4][2];
        #pragma unroll
        for (int n = 0; n < 4; ++n) { acc[n][0] = 0.f; acc[n][1] = 0.f; }
        for (int k = 0; k < HID; k += 4) {
            float w2a[4], w2b[4];
            #pragma unroll
            for (int j = 0; j < 4; ++j) {
                w2a[j] = W2[(k + j) * C + c0];
                w2b[j] = W2[(k + j) * C + c0 + 64];
            }
            #pragma unroll
            for (int n = 0; n < 4; ++n) {
                const float4 h4 = *reinterpret_cast<const float4*>(&hS[g * 4 + n][k]);
                acc[n][0] += h4.x * w2a[0] + h4.y * w2a[1] + h4.z * w2a[2] + h4.w * w2a[3];
                acc[n][1] += h4.x * w2b[0] + h4.y * w2b[1] + h4.z * w2b[2] + h4.w * w2b[3];
            }
        }
        const float bb0 = b2[c0];
        const float bb1 = b2[c0 + 64];
        #pragma unroll
        for (int n = 0; n < 4; ++n) {
            long node = base + g * 4 + n;
            if (node < N) {
                io[node * C + c0]      = acc[n][0] + bb0;
                io[node * C + c0 + 64] = acc[n][1] + bb1;
            }
        }
    }
}

extern "C" void kernel_launch(void* const* d_in, const int* in_sizes, int n_in,
                              void* d_out, int out_size, void* d_ws, size_t ws_size,
                              hipStream_t stream) {
    const float* x  = (const float*)d_in[0];
    const int*   ei = (const int*)d_in[1];
    const float* ea = (const float*)d_in[2];
    const float* W1 = (const float*)d_in[3];
    const float* b1 = (const float*)d_in[4];
    const float* W2 = (const float*)d_in[5];
    const float* b2 = (const float*)d_in[6];
    float* out = (float*)d_out;
    const int N = in_sizes[0] / C;
    const int E = in_sizes[2];
    float* deg = (float*)d_ws;

    // agg accumulates directly in d_out; deg in workspace. Zero both.
    hipMemsetAsync(out, 0, (size_t)N * C * sizeof(float), stream);
    hipMemsetAsync(deg, 0, (size_t)N * sizeof(float), stream);

    edge_scatter<<<(E + 1) / 2, 256, 0, stream>>>(x, ei, ea, out, deg, E);
    node_mlp<<<(N + NPB - 1) / NPB, 256, 0, stream>>>(x, deg, W1, b1, W2, b2, out, N);
}

// Round 2
// 316.575 us; speedup vs baseline: 1.6564x; 1.6564x over previous
//
#include <hip/hip_runtime.h>

#define C 128
#define HID 256
#define NPB 16   // nodes per block in node_mlp

// ---------- CSR build ----------

__global__ __launch_bounds__(256) void hist_kernel(
    const int* __restrict__ ei, int* __restrict__ deg_i, int E)
{
    int e = blockIdx.x * 256 + threadIdx.x;
    if (e < E) atomicAdd(&deg_i[ei[E + e]], 1);
}

__global__ __launch_bounds__(256) void scan_bsum(
    const int* __restrict__ deg_i, int* __restrict__ bsums, int N)
{
    __shared__ int s[256];
    int t = threadIdx.x;
    int i = blockIdx.x * 256 + t;
    s[t] = (i < N) ? deg_i[i] : 0;
    __syncthreads();
    for (int off = 128; off > 0; off >>= 1) {
        if (t < off) s[t] += s[t + off];
        __syncthreads();
    }
    if (t == 0) bsums[blockIdx.x] = s[0];
}

__global__ __launch_bounds__(256) void scan_top(int* __restrict__ bsums, int nb)
{
    __shared__ int s[256];
    int t = threadIdx.x;
    int orig = (t < nb) ? bsums[t] : 0;
    s[t] = orig;
    __syncthreads();
    for (int off = 1; off < 256; off <<= 1) {
        int v = (t >= off) ? s[t - off] : 0;
        __syncthreads();
        s[t] += v;
        __syncthreads();
    }
    if (t < nb) bsums[t] = s[t] - orig;   // exclusive
}

__global__ __launch_bounds__(256) void scan_final(
    const int* __restrict__ deg_i, const int* __restrict__ bsums,
    int* __restrict__ offs, int* __restrict__ cursor, int N)
{
    __shared__ int s[256];
    int t = threadIdx.x;
    int i = blockIdx.x * 256 + t;
    int orig = (i < N) ? deg_i[i] : 0;
    s[t] = orig;
    __syncthreads();
    for (int off = 1; off < 256; off <<= 1) {
        int v = (t >= off) ? s[t - off] : 0;
        __syncthreads();
        s[t] += v;
        __syncthreads();
    }
    if (i < N) {
        int excl = s[t] - orig + bsums[blockIdx.x];
        offs[i] = excl;
        cursor[i] = excl;
    }
}

__global__ __launch_bounds__(256) void scatter_edges(
    const int* __restrict__ ei, const float* __restrict__ ea,
    int* __restrict__ cursor, int* __restrict__ src_s,
    float* __restrict__ w_s, int E)
{
    int e = blockIdx.x * 256 + threadIdx.x;
    if (e < E) {
        int dst = ei[E + e];
        int pos = atomicAdd(&cursor[dst], 1);
        src_s[pos] = ei[e];
        w_s[pos]   = ea[e];
    }
}

// ---------- fused aggregate + MLP ----------

__global__ __launch_bounds__(256) void node_mlp(
    const float* __restrict__ x, const int* __restrict__ offs,
    const int* __restrict__ deg_i, const int* __restrict__ src_s,
    const float* __restrict__ w_s,
    const float* __restrict__ W1, const float* __restrict__ b1,
    const float* __restrict__ W2, const float* __restrict__ b2,
    float* __restrict__ out, int N)
{
    __shared__ float outS[NPB][C];    // 8 KB
    __shared__ float hS[NPB][HID];    // 16 KB
    const int t = threadIdx.x;
    const int base = blockIdx.x * NPB;

    // ---- Phase A: CSR gather-aggregate + 0.5*(x+agg/deg) into LDS ----
    {
        const int nl = t >> 7;        // which of 2 nodes in flight
        const int c  = t & 127;
        for (int p = 0; p < NPB / 2; ++p) {
            int node = base + p * 2 + nl;
            float v = 0.f;
            if (node < N) {
                int rs = offs[node];
                int d  = deg_i[node];
                float acc = 0.f;
                int j = 0;
                for (; j + 1 < d; j += 2) {
                    int   s0 = src_s[rs + j],  s1 = src_s[rs + j + 1];
                    float w0 = w_s[rs + j],    w1 = w_s[rs + j + 1];
                    acc = fmaf(x[s0 * C + c], w0, acc);
                    acc = fmaf(x[s1 * C + c], w1, acc);
                }
                if (j < d) {
                    acc = fmaf(x[src_s[rs + j] * C + c], w_s[rs + j], acc);
                }
                float dd = (d > 0) ? (float)d : 1.f;
                v = 0.5f * (x[node * C + c] + acc / dd);
            }
            outS[p * 2 + nl][c] = v;
        }
    }
    __syncthreads();

    // ---- Phase B: h = relu(out @ W1 + b1), thread = (col c0, c0+128) x 8 nodes ----
    {
        const int c0 = t & 127;
        const int g  = t >> 7;          // 2 groups of 8 nodes
        float acc[8][2];
        #pragma unroll
        for (int n = 0; n < 8; ++n) { acc[n][0] = 0.f; acc[n][1] = 0.f; }
        for (int k = 0; k < C; k += 4) {
            float w1a[4], w1b[4];
            #pragma unroll
            for (int j = 0; j < 4; ++j) {
                w1a[j] = W1[(k + j) * HID + c0];
                w1b[j] = W1[(k + j) * HID + c0 + 128];
            }
            #pragma unroll
            for (int n = 0; n < 8; ++n) {
                const float4 o4 = *reinterpret_cast<const float4*>(&outS[g * 8 + n][k]);
                acc[n][0] += o4.x * w1a[0] + o4.y * w1a[1] + o4.z * w1a[2] + o4.w * w1a[3];
                acc[n][1] += o4.x * w1b[0] + o4.y * w1b[1] + o4.z * w1b[2] + o4.w * w1b[3];
            }
        }
        const float bb0 = b1[c0];
        const float bb1 = b1[c0 + 128];
        #pragma unroll
        for (int n = 0; n < 8; ++n) {
            hS[g * 8 + n][c0]       = fmaxf(acc[n][0] + bb0, 0.f);
            hS[g * 8 + n][c0 + 128] = fmaxf(acc[n][1] + bb1, 0.f);
        }
    }
    __syncthreads();

    // ---- Phase C: y = h @ W2 + b2, thread = (col c0, c0+64) x 4 nodes ----
    {
        const int c0 = t & 63;
        const int g  = t >> 6;          // 4 groups of 4 nodes
        float acc[4][2];
        #pragma unroll
        for (int n = 0; n < 4; ++n) { acc[n][0] = 0.f; acc[n][1] = 0.f; }
        for (int k = 0; k < HID; k += 4) {
            float w2a[4], w2b[4];
            #pragma unroll
            for (int j = 0; j < 4; ++j) {
                w2a[j] = W2[(k + j) * C + c0];
                w2b[j] = W2[(k + j) * C + c0 + 64];
            }
            #pragma unroll
            for (int n = 0; n < 4; ++n) {
                const float4 h4 = *reinterpret_cast<const float4*>(&hS[g * 4 + n][k]);
                acc[n][0] += h4.x * w2a[0] + h4.y * w2a[1] + h4.z * w2a[2] + h4.w * w2a[3];
                acc[n][1] += h4.x * w2b[0] + h4.y * w2b[1] + h4.z * w2b[2] + h4.w * w2b[3];
            }
        }
        const float bb0 = b2[c0];
        const float bb1 = b2[c0 + 64];
        #pragma unroll
        for (int n = 0; n < 4; ++n) {
            int node = base + g * 4 + n;
            if (node < N) {
                out[node * C + c0]      = acc[n][0] + bb0;
                out[node * C + c0 + 64] = acc[n][1] + bb1;
            }
        }
    }
}

extern "C" void kernel_launch(void* const* d_in, const int* in_sizes, int n_in,
                              void* d_out, int out_size, void* d_ws, size_t ws_size,
                              hipStream_t stream) {
    const float* x  = (const float*)d_in[0];
    const int*   ei = (const int*)d_in[1];
    const float* ea = (const float*)d_in[2];
    const float* W1 = (const float*)d_in[3];
    const float* b1 = (const float*)d_in[4];
    const float* W2 = (const float*)d_in[5];
    const float* b2 = (const float*)d_in[6];
    float* out = (float*)d_out;
    const int N = in_sizes[0] / C;
    const int E = in_sizes[2];

    // workspace layout
    int* deg_i  = (int*)d_ws;            // N
    int* offs   = deg_i + N;             // N
    int* cursor = offs + N;              // N
    int* bsums  = cursor + N;            // 256
    int* src_s  = bsums + 256;           // E
    float* w_s  = (float*)(src_s + E);   // E

    const int nb = (N + 255) / 256;      // 196 <= 256

    hipMemsetAsync(deg_i, 0, (size_t)N * sizeof(int), stream);
    hist_kernel<<<(E + 255) / 256, 256, 0, stream>>>(ei, deg_i, E);
    scan_bsum<<<nb, 256, 0, stream>>>(deg_i, bsums, N);
    scan_top<<<1, 256, 0, stream>>>(bsums, nb);
    scan_final<<<nb, 256, 0, stream>>>(deg_i, bsums, offs, cursor, N);
    scatter_edges<<<(E + 255) / 256, 256, 0, stream>>>(ei, ea, cursor, src_s, w_s, E);
    node_mlp<<<(N + NPB - 1) / NPB, 256, 0, stream>>>(
        x, offs, deg_i, src_s, w_s, W1, b1, W2, b2, out, N);
}

// Round 3
// 192.440 us; speedup vs baseline: 2.7249x; 1.6451x over previous
//
#include <hip/hip_runtime.h>

#define C 128
#define HID 256
#define MT 64   // nodes per block in mlp_mfma

typedef __attribute__((ext_vector_type(8))) short bf16x8;
typedef __attribute__((ext_vector_type(4))) short s16x4;
typedef __attribute__((ext_vector_type(4))) float f32x4;

__device__ inline unsigned short f2b(float f) {
    unsigned u = __builtin_bit_cast(unsigned, f);
    unsigned r = u + 0x7fffu + ((u >> 16) & 1u);
    return (unsigned short)(r >> 16);
}

// ---------- CSR build ----------

__global__ __launch_bounds__(256) void hist_kernel(
    const int* __restrict__ ei, int* __restrict__ deg_i, int E)
{
    int e = blockIdx.x * 256 + threadIdx.x;
    if (e < E) atomicAdd(&deg_i[ei[E + e]], 1);
}

__global__ __launch_bounds__(256) void scan_bsum(
    const int* __restrict__ deg_i, int* __restrict__ bsums, int N)
{
    __shared__ int s[256];
    int t = threadIdx.x;
    int i = blockIdx.x * 256 + t;
    s[t] = (i < N) ? deg_i[i] : 0;
    __syncthreads();
    for (int off = 128; off > 0; off >>= 1) {
        if (t < off) s[t] += s[t + off];
        __syncthreads();
    }
    if (t == 0) bsums[blockIdx.x] = s[0];
}

__global__ __launch_bounds__(256) void scan_top(int* __restrict__ bsums, int nb)
{
    __shared__ int s[256];
    int t = threadIdx.x;
    int orig = (t < nb) ? bsums[t] : 0;
    s[t] = orig;
    __syncthreads();
    for (int off = 1; off < 256; off <<= 1) {
        int v = (t >= off) ? s[t - off] : 0;
        __syncthreads();
        s[t] += v;
        __syncthreads();
    }
    if (t < nb) bsums[t] = s[t] - orig;   // exclusive
}

__global__ __launch_bounds__(256) void scan_final(
    const int* __restrict__ deg_i, const int* __restrict__ bsums,
    int* __restrict__ offs, int* __restrict__ cursor, int N)
{
    __shared__ int s[256];
    int t = threadIdx.x;
    int i = blockIdx.x * 256 + t;
    int orig = (i < N) ? deg_i[i] : 0;
    s[t] = orig;
    __syncthreads();
    for (int off = 1; off < 256; off <<= 1) {
        int v = (t >= off) ? s[t - off] : 0;
        __syncthreads();
        s[t] += v;
        __syncthreads();
    }
    if (i < N) {
        int excl = s[t] - orig + bsums[blockIdx.x];
        offs[i] = excl;
        cursor[i] = excl;
    }
}

__global__ __launch_bounds__(256) void scatter_edges(
    const int* __restrict__ ei, const float* __restrict__ ea,
    int* __restrict__ cursor, uint2* __restrict__ src_w, int E)
{
    int e = blockIdx.x * 256 + threadIdx.x;
    if (e < E) {
        int dst = ei[E + e];
        int pos = atomicAdd(&cursor[dst], 1);
        uint2 rec;
        rec.x = (unsigned)ei[e];
        rec.y = __builtin_bit_cast(unsigned, ea[e]);
        src_w[pos] = rec;
    }
}

// ---------- weight convert + permute into MFMA B-fragment order ----------
// frag layout: lane l, elem j holds B[k][n] with n = nt*16+(l&15),
//              k = kk*32 + 16*(j>>2) + 4*(l>>4) + (j&3)
// W1p flat idx: ((nt*4+kk)*64 + l)*8 + j   (nt<16, kk<4)
// W2p flat idx: ((nt*8+kk)*64 + l)*8 + j   (nt<8,  kk<8)

__global__ __launch_bounds__(256) void convert_w(
    const float* __restrict__ W1, const float* __restrict__ W2,
    unsigned short* __restrict__ W1p, unsigned short* __restrict__ W2p)
{
    int t = blockIdx.x * 256 + threadIdx.x;
    if (t < C * HID) {
        {
            int j = t & 7, l = (t >> 3) & 63, kk = (t >> 9) & 3, nt = t >> 11;
            int n = nt * 16 + (l & 15);
            int k = kk * 32 + 16 * (j >> 2) + 4 * (l >> 4) + (j & 3);
            W1p[t] = f2b(W1[k * HID + n]);
        }
        {
            int j = t & 7, l = (t >> 3) & 63, kk = (t >> 9) & 7, nt = t >> 12;
            int n = nt * 16 + (l & 15);
            int k = kk * 32 + 16 * (j >> 2) + 4 * (l >> 4) + (j & 3);
            W2p[t] = f2b(W2[k * C + n]);
        }
    }
}

// ---------- per-node CSR aggregation -> out0 (bf16) ----------

__global__ __launch_bounds__(256) void node_agg(
    const float* __restrict__ x, const int* __restrict__ offs,
    const int* __restrict__ deg_i, const uint2* __restrict__ src_w,
    unsigned short* __restrict__ out0, int N)
{
    const int lane = threadIdx.x & 63;
    const int wid  = threadIdx.x >> 6;
    const int node = blockIdx.x * 4 + wid;
    if (node >= N) return;
    const int rs = offs[node];
    const int d  = deg_i[node];
    const int c  = lane * 2;
    float a0 = 0.f, a1 = 0.f;
    int j = 0;
    for (; j + 4 <= d; j += 4) {
        uint2 e0 = src_w[rs + j];
        uint2 e1 = src_w[rs + j + 1];
        uint2 e2 = src_w[rs + j + 2];
        uint2 e3 = src_w[rs + j + 3];
        float2 v0 = *(const float2*)(x + (long)e0.x * C + c);
        float2 v1 = *(const float2*)(x + (long)e1.x * C + c);
        float2 v2 = *(const float2*)(x + (long)e2.x * C + c);
        float2 v3 = *(const float2*)(x + (long)e3.x * C + c);
        float w0 = __builtin_bit_cast(float, e0.y);
        float w1 = __builtin_bit_cast(float, e1.y);
        float w2 = __builtin_bit_cast(float, e2.y);
        float w3 = __builtin_bit_cast(float, e3.y);
        a0 = fmaf(v0.x, w0, a0); a1 = fmaf(v0.y, w0, a1);
        a0 = fmaf(v1.x, w1, a0); a1 = fmaf(v1.y, w1, a1);
        a0 = fmaf(v2.x, w2, a0); a1 = fmaf(v2.y, w2, a1);
        a0 = fmaf(v3.x, w3, a0); a1 = fmaf(v3.y, w3, a1);
    }
    for (; j < d; ++j) {
        uint2 e = src_w[rs + j];
        float2 v = *(const float2*)(x + (long)e.x * C + c);
        float w = __builtin_bit_cast(float, e.y);
        a0 = fmaf(v.x, w, a0); a1 = fmaf(v.y, w, a1);
    }
    float dd  = (d > 0) ? (float)d : 1.f;
    float inv = 1.f / dd;
    float2 xv = *(const float2*)(x + (long)node * C + c);
    float o0 = 0.5f * (xv.x + a0 * inv);
    float o1 = 0.5f * (xv.y + a1 * inv);
    unsigned pack = (unsigned)f2b(o0) | ((unsigned)f2b(o1) << 16);
    *(unsigned*)(out0 + (long)node * C + c) = pack;
}

// ---------- MFMA MLP: y = relu(out0 @ W1 + b1) @ W2 + b2 ----------

__global__ __launch_bounds__(256) void mlp_mfma(
    const unsigned short* __restrict__ out0,
    const unsigned short* __restrict__ W1p, const float* __restrict__ b1,
    const unsigned short* __restrict__ W2p, const float* __restrict__ b2,
    float* __restrict__ out, int N)
{
    __shared__ unsigned short hS[4][16][264];   // per-wave h tile, padded stride
    const int lane = threadIdx.x & 63;
    const int wid  = threadIdx.x >> 6;
    const int r16  = lane & 15;
    const int grp  = lane >> 4;
    const int nodeBase = blockIdx.x * MT + wid * 16;

    // A-fragments for GEMM1 from out0 (row = node, K = 128 in 4 chunks of 32)
    bf16x8 a1[4];
    {
        int arow = nodeBase + r16;
        if (arow >= N) arow = N - 1;   // clamp; results discarded by store guard
        const unsigned short* ar = out0 + (long)arow * C;
        #pragma unroll
        for (int kk = 0; kk < 4; ++kk) {
            s16x4 lo = *(const s16x4*)(ar + kk * 32 + 4 * grp);
            s16x4 hi = *(const s16x4*)(ar + kk * 32 + 16 + 4 * grp);
            bf16x8 a;
            a[0] = lo[0]; a[1] = lo[1]; a[2] = lo[2]; a[3] = lo[3];
            a[4] = hi[0]; a[5] = hi[1]; a[6] = hi[2]; a[7] = hi[3];
            a1[kk] = a;
        }
    }

    // GEMM1: h = relu(out0 @ W1 + b1) -> hS (bf16)
    #pragma unroll 4
    for (int nt = 0; nt < 16; ++nt) {
        f32x4 acc = {0.f, 0.f, 0.f, 0.f};
        #pragma unroll
        for (int kk = 0; kk < 4; ++kk) {
            bf16x8 b = *(const bf16x8*)(W1p + (((nt * 4 + kk) * 64 + lane) << 3));
            acc = __builtin_amdgcn_mfma_f32_16x16x32_bf16(a1[kk], b, acc, 0, 0, 0);
        }
        float bias = b1[nt * 16 + r16];          // C-frag: col = lane&15
        #pragma unroll
        for (int r = 0; r < 4; ++r) {            // row = 4*(lane>>4)+r
            float h = fmaxf(acc[r] + bias, 0.f);
            hS[wid][grp * 4 + r][nt * 16 + r16] = f2b(h);
        }
    }

    __syncthreads();   // cheap safety: hS cross-lane RAW

    // A-fragments for GEMM2 from hS (row = node, K = 256 in 8 chunks)
    bf16x8 a2[8];
    #pragma unroll
    for (int kk = 0; kk < 8; ++kk) {
        s16x4 lo = *(const s16x4*)&hS[wid][r16][kk * 32 + 4 * grp];
        s16x4 hi = *(const s16x4*)&hS[wid][r16][kk * 32 + 16 + 4 * grp];
        bf16x8 a;
        a[0] = lo[0]; a[1] = lo[1]; a[2] = lo[2]; a[3] = lo[3];
        a[4] = hi[0]; a[5] = hi[1]; a[6] = hi[2]; a[7] = hi[3];
        a2[kk] = a;
    }

    // GEMM2: y = h @ W2 + b2 -> out
    #pragma unroll 2
    for (int nt = 0; nt < 8; ++nt) {
        f32x4 acc = {0.f, 0.f, 0.f, 0.f};
        #pragma unroll
        for (int kk = 0; kk < 8; ++kk) {
            bf16x8 b = *(const bf16x8*)(W2p + (((nt * 8 + kk) * 64 + lane) << 3));
            acc = __builtin_amdgcn_mfma_f32_16x16x32_bf16(a2[kk], b, acc, 0, 0, 0);
        }
        float bias = b2[nt * 16 + r16];
        #pragma unroll
        for (int r = 0; r < 4; ++r) {
            int node = nodeBase + grp * 4 + r;
            if (node < N) out[(long)node * C + nt * 16 + r16] = acc[r] + bias;
        }
    }
}

extern "C" void kernel_launch(void* const* d_in, const int* in_sizes, int n_in,
                              void* d_out, int out_size, void* d_ws, size_t ws_size,
                              hipStream_t stream) {
    const float* x  = (const float*)d_in[0];
    const int*   ei = (const int*)d_in[1];
    const float* ea = (const float*)d_in[2];
    const float* W1 = (const float*)d_in[3];
    const float* b1 = (const float*)d_in[4];
    const float* W2 = (const float*)d_in[5];
    const float* b2 = (const float*)d_in[6];
    float* out = (float*)d_out;
    const int N = in_sizes[0] / C;
    const int E = in_sizes[2];

    // workspace layout (bytes, all 16B-aligned for N=50000, E=800000)
    char* p = (char*)d_ws;
    int* deg_i  = (int*)p;                 p += (size_t)N * 4;
    int* offs   = (int*)p;                 p += (size_t)N * 4;
    int* cursor = (int*)p;                 p += (size_t)N * 4;
    int* bsums  = (int*)p;                 p += 256 * 4;
    uint2* src_w = (uint2*)p;              p += (size_t)E * 8;
    unsigned short* out0 = (unsigned short*)p;  p += (size_t)N * C * 2;
    unsigned short* W1p  = (unsigned short*)p;  p += (size_t)C * HID * 2;
    unsigned short* W2p  = (unsigned short*)p;

    const int nb = (N + 255) / 256;

    hipMemsetAsync(deg_i, 0, (size_t)N * sizeof(int), stream);
    convert_w<<<(C * HID + 255) / 256, 256, 0, stream>>>(W1, W2, W1p, W2p);
    hist_kernel<<<(E + 255) / 256, 256, 0, stream>>>(ei, deg_i, E);
    scan_bsum<<<nb, 256, 0, stream>>>(deg_i, bsums, N);
    scan_top<<<1, 256, 0, stream>>>(bsums, nb);
    scan_final<<<nb, 256, 0, stream>>>(deg_i, bsums, offs, cursor, N);
    scatter_edges<<<(E + 255) / 256, 256, 0, stream>>>(ei, ea, cursor, src_w, E);
    node_agg<<<(N + 3) / 4, 256, 0, stream>>>(x, offs, deg_i, src_w, out0, N);
    mlp_mfma<<<(N + MT - 1) / MT, 256, 0, stream>>>(out0, W1p, b1, W2p, b2, out, N);
}

// Round 4
// 180.766 us; speedup vs baseline: 2.9009x; 1.0646x over previous
//
#include <hip/hip_runtime.h>

#define C 128
#define HID 256
#define MT 64   // nodes per block in mlp_mfma

typedef __attribute__((ext_vector_type(8))) short bf16x8;
typedef __attribute__((ext_vector_type(4))) short s16x4;
typedef __attribute__((ext_vector_type(4))) float f32x4;

__device__ inline unsigned short f2b(float f) {
    unsigned u = __builtin_bit_cast(unsigned, f);
    unsigned r = u + 0x7fffu + ((u >> 16) & 1u);
    return (unsigned short)(r >> 16);
}

// ---------- x -> bf16 copy (shrinks gather working set 2x) ----------

__global__ __launch_bounds__(256) void convert_x(
    const float* __restrict__ x, unsigned short* __restrict__ xb, long total4)
{
    long i = (long)blockIdx.x * 256 + threadIdx.x;
    if (i < total4) {
        float4 v = *(const float4*)(x + i * 4);
        ushort4 o;
        o.x = f2b(v.x); o.y = f2b(v.y); o.z = f2b(v.z); o.w = f2b(v.w);
        *(ushort4*)(xb + i * 4) = o;
    }
}

// ---------- CSR build ----------

__global__ __launch_bounds__(256) void hist_kernel(
    const int* __restrict__ ei, int* __restrict__ deg_i, int E)
{
    int e = blockIdx.x * 256 + threadIdx.x;
    if (e < E) atomicAdd(&deg_i[ei[E + e]], 1);
}

__global__ __launch_bounds__(256) void scan_bsum(
    const int* __restrict__ deg_i, int* __restrict__ bsums, int N)
{
    __shared__ int s[256];
    int t = threadIdx.x;
    int i = blockIdx.x * 256 + t;
    s[t] = (i < N) ? deg_i[i] : 0;
    __syncthreads();
    for (int off = 128; off > 0; off >>= 1) {
        if (t < off) s[t] += s[t + off];
        __syncthreads();
    }
    if (t == 0) bsums[blockIdx.x] = s[0];
}

__global__ __launch_bounds__(256) void scan_top(int* __restrict__ bsums, int nb)
{
    __shared__ int s[256];
    int t = threadIdx.x;
    int orig = (t < nb) ? bsums[t] : 0;
    s[t] = orig;
    __syncthreads();
    for (int off = 1; off < 256; off <<= 1) {
        int v = (t >= off) ? s[t - off] : 0;
        __syncthreads();
        s[t] += v;
        __syncthreads();
    }
    if (t < nb) bsums[t] = s[t] - orig;   // exclusive
}

__global__ __launch_bounds__(256) void scan_final(
    const int* __restrict__ deg_i, const int* __restrict__ bsums,
    int* __restrict__ offs, int* __restrict__ cursor, int N)
{
    __shared__ int s[256];
    int t = threadIdx.x;
    int i = blockIdx.x * 256 + t;
    int orig = (i < N) ? deg_i[i] : 0;
    s[t] = orig;
    __syncthreads();
    for (int off = 1; off < 256; off <<= 1) {
        int v = (t >= off) ? s[t - off] : 0;
        __syncthreads();
        s[t] += v;
        __syncthreads();
    }
    if (i < N) {
        int excl = s[t] - orig + bsums[blockIdx.x];
        offs[i] = excl;
        cursor[i] = excl;
    }
}

__global__ __launch_bounds__(256) void scatter_edges(
    const int* __restrict__ ei, const float* __restrict__ ea,
    int* __restrict__ cursor, uint2* __restrict__ src_w, int E)
{
    int e = blockIdx.x * 256 + threadIdx.x;
    if (e < E) {
        int dst = ei[E + e];
        int pos = atomicAdd(&cursor[dst], 1);
        uint2 rec;
        rec.x = (unsigned)ei[e];
        rec.y = __builtin_bit_cast(unsigned, ea[e]);
        src_w[pos] = rec;
    }
}

// ---------- weight convert + permute into MFMA B-fragment order ----------
// frag layout: lane l, elem j holds B[k][n] with n = nt*16+(l&15),
//              k = kk*32 + 16*(j>>2) + 4*(l>>4) + (j&3)

__global__ __launch_bounds__(256) void convert_w(
    const float* __restrict__ W1, const float* __restrict__ W2,
    unsigned short* __restrict__ W1p, unsigned short* __restrict__ W2p)
{
    int t = blockIdx.x * 256 + threadIdx.x;
    if (t < C * HID) {
        {
            int j = t & 7, l = (t >> 3) & 63, kk = (t >> 9) & 3, nt = t >> 11;
            int n = nt * 16 + (l & 15);
            int k = kk * 32 + 16 * (j >> 2) + 4 * (l >> 4) + (j & 3);
            W1p[t] = f2b(W1[k * HID + n]);
        }
        {
            int j = t & 7, l = (t >> 3) & 63, kk = (t >> 9) & 7, nt = t >> 12;
            int n = nt * 16 + (l & 15);
            int k = kk * 32 + 16 * (j >> 2) + 4 * (l >> 4) + (j & 3);
            W2p[t] = f2b(W2[k * C + n]);
        }
    }
}

// ---------- per-node CSR aggregation (bf16 gather) -> out0 (bf16) ----------

__global__ __launch_bounds__(256) void node_agg(
    const float* __restrict__ x, const unsigned short* __restrict__ xb,
    const int* __restrict__ offs, const int* __restrict__ deg_i,
    const uint2* __restrict__ src_w, unsigned short* __restrict__ out0, int N)
{
    const int lane = threadIdx.x & 63;
    const int wid  = threadIdx.x >> 6;
    const int node = blockIdx.x * 4 + wid;
    if (node >= N) return;
    const int rs = offs[node];
    const int d  = deg_i[node];
    const int c  = lane * 2;
    float a0 = 0.f, a1 = 0.f;
    int j = 0;
    for (; j + 8 <= d; j += 8) {
        uint2 e[8];
        #pragma unroll
        for (int i = 0; i < 8; ++i) e[i] = src_w[rs + j + i];
        unsigned v[8];
        #pragma unroll
        for (int i = 0; i < 8; ++i)
            v[i] = *(const unsigned*)(xb + (long)e[i].x * C + c);
        #pragma unroll
        for (int i = 0; i < 8; ++i) {
            float w  = __builtin_bit_cast(float, e[i].y);
            float f0 = __builtin_bit_cast(float, v[i] << 16);
            float f1 = __builtin_bit_cast(float, v[i] & 0xffff0000u);
            a0 = fmaf(f0, w, a0);
            a1 = fmaf(f1, w, a1);
        }
    }
    for (; j < d; ++j) {
        uint2 e = src_w[rs + j];
        unsigned v = *(const unsigned*)(xb + (long)e.x * C + c);
        float w = __builtin_bit_cast(float, e.y);
        a0 = fmaf(__builtin_bit_cast(float, v << 16), w, a0);
        a1 = fmaf(__builtin_bit_cast(float, v & 0xffff0000u), w, a1);
    }
    float dd  = (d > 0) ? (float)d : 1.f;
    float inv = 1.f / dd;
    float2 xv = *(const float2*)(x + (long)node * C + c);
    float o0 = 0.5f * (xv.x + a0 * inv);
    float o1 = 0.5f * (xv.y + a1 * inv);
    unsigned pack = (unsigned)f2b(o0) | ((unsigned)f2b(o1) << 16);
    *(unsigned*)(out0 + (long)node * C + c) = pack;
}

// ---------- MFMA MLP: y = relu(out0 @ W1 + b1) @ W2 + b2 ----------

__global__ __launch_bounds__(256) void mlp_mfma(
    const unsigned short* __restrict__ out0,
    const unsigned short* __restrict__ W1p, const float* __restrict__ b1,
    const unsigned short* __restrict__ W2p, const float* __restrict__ b2,
    float* __restrict__ out, int N)
{
    __shared__ unsigned short hS[4][16][264];   // per-wave h tile, padded stride
    const int lane = threadIdx.x & 63;
    const int wid  = threadIdx.x >> 6;
    const int r16  = lane & 15;
    const int grp  = lane >> 4;
    const int nodeBase = blockIdx.x * MT + wid * 16;

    // A-fragments for GEMM1 from out0 (row = node, K = 128 in 4 chunks of 32)
    bf16x8 a1[4];
    {
        int arow = nodeBase + r16;
        if (arow >= N) arow = N - 1;   // clamp; results discarded by store guard
        const unsigned short* ar = out0 + (long)arow * C;
        #pragma unroll
        for (int kk = 0; kk < 4; ++kk) {
            s16x4 lo = *(const s16x4*)(ar + kk * 32 + 4 * grp);
            s16x4 hi = *(const s16x4*)(ar + kk * 32 + 16 + 4 * grp);
            bf16x8 a;
            a[0] = lo[0]; a[1] = lo[1]; a[2] = lo[2]; a[3] = lo[3];
            a[4] = hi[0]; a[5] = hi[1]; a[6] = hi[2]; a[7] = hi[3];
            a1[kk] = a;
        }
    }

    // GEMM1: h = relu(out0 @ W1 + b1) -> hS (bf16)
    #pragma unroll 4
    for (int nt = 0; nt < 16; ++nt) {
        f32x4 acc = {0.f, 0.f, 0.f, 0.f};
        #pragma unroll
        for (int kk = 0; kk < 4; ++kk) {
            bf16x8 b = *(const bf16x8*)(W1p + (((nt * 4 + kk) * 64 + lane) << 3));
            acc = __builtin_amdgcn_mfma_f32_16x16x32_bf16(a1[kk], b, acc, 0, 0, 0);
        }
        float bias = b1[nt * 16 + r16];          // C-frag: col = lane&15
        #pragma unroll
        for (int r = 0; r < 4; ++r) {            // row = 4*(lane>>4)+r
            float h = fmaxf(acc[r] + bias, 0.f);
            hS[wid][grp * 4 + r][nt * 16 + r16] = f2b(h);
        }
    }

    __syncthreads();   // hS cross-lane RAW

    // A-fragments for GEMM2 from hS (row = node, K = 256 in 8 chunks)
    bf16x8 a2[8];
    #pragma unroll
    for (int kk = 0; kk < 8; ++kk) {
        s16x4 lo = *(const s16x4*)&hS[wid][r16][kk * 32 + 4 * grp];
        s16x4 hi = *(const s16x4*)&hS[wid][r16][kk * 32 + 16 + 4 * grp];
        bf16x8 a;
        a[0] = lo[0]; a[1] = lo[1]; a[2] = lo[2]; a[3] = lo[3];
        a[4] = hi[0]; a[5] = hi[1]; a[6] = hi[2]; a[7] = hi[3];
        a2[kk] = a;
    }

    // GEMM2: y = h @ W2 + b2 -> out
    #pragma unroll 2
    for (int nt = 0; nt < 8; ++nt) {
        f32x4 acc = {0.f, 0.f, 0.f, 0.f};
        #pragma unroll
        for (int kk = 0; kk < 8; ++kk) {
            bf16x8 b = *(const bf16x8*)(W2p + (((nt * 8 + kk) * 64 + lane) << 3));
            acc = __builtin_amdgcn_mfma_f32_16x16x32_bf16(a2[kk], b, acc, 0, 0, 0);
        }
        float bias = b2[nt * 16 + r16];
        #pragma unroll
        for (int r = 0; r < 4; ++r) {
            int node = nodeBase + grp * 4 + r;
            if (node < N) out[(long)node * C + nt * 16 + r16] = acc[r] + bias;
        }
    }
}

extern "C" void kernel_launch(void* const* d_in, const int* in_sizes, int n_in,
                              void* d_out, int out_size, void* d_ws, size_t ws_size,
                              hipStream_t stream) {
    const float* x  = (const float*)d_in[0];
    const int*   ei = (const int*)d_in[1];
    const float* ea = (const float*)d_in[2];
    const float* W1 = (const float*)d_in[3];
    const float* b1 = (const float*)d_in[4];
    const float* W2 = (const float*)d_in[5];
    const float* b2 = (const float*)d_in[6];
    float* out = (float*)d_out;
    const int N = in_sizes[0] / C;
    const int E = in_sizes[2];

    // workspace layout (all 16B-aligned for N=50000, E=800000)
    char* p = (char*)d_ws;
    int* deg_i  = (int*)p;                 p += (size_t)N * 4;
    int* offs   = (int*)p;                 p += (size_t)N * 4;
    int* cursor = (int*)p;                 p += (size_t)N * 4;
    int* bsums  = (int*)p;                 p += 256 * 4;
    uint2* src_w = (uint2*)p;              p += (size_t)E * 8;
    unsigned short* out0 = (unsigned short*)p;  p += (size_t)N * C * 2;
    unsigned short* W1p  = (unsigned short*)p;  p += (size_t)C * HID * 2;
    unsigned short* W2p  = (unsigned short*)p;  p += (size_t)HID * C * 2;
    unsigned short* xb   = (unsigned short*)p;  // N*C*2

    const int nb = (N + 255) / 256;
    const long total4 = ((long)N * C) / 4;

    hipMemsetAsync(deg_i, 0, (size_t)N * sizeof(int), stream);
    convert_x<<<(int)((total4 + 255) / 256), 256, 0, stream>>>(x, xb, total4);
    convert_w<<<(C * HID + 255) / 256, 256, 0, stream>>>(W1, W2, W1p, W2p);
    hist_kernel<<<(E + 255) / 256, 256, 0, stream>>>(ei, deg_i, E);
    scan_bsum<<<nb, 256, 0, stream>>>(deg_i, bsums, N);
    scan_top<<<1, 256, 0, stream>>>(bsums, nb);
    scan_final<<<nb, 256, 0, stream>>>(deg_i, bsums, offs, cursor, N);
    scatter_edges<<<(E + 255) / 256, 256, 0, stream>>>(ei, ea, cursor, src_w, E);
    node_agg<<<(N + 3) / 4, 256, 0, stream>>>(x, xb, offs, deg_i, src_w, out0, N);
    mlp_mfma<<<(N + MT - 1) / MT, 256, 0, stream>>>(out0, W1p, b1, W2p, b2, out, N);
}